// Round 2
// baseline (228.631 us; speedup 1.0000x reference)
//
#include <hip/hip_runtime.h>

// PermuteWeightSharing: out[row, s*16+k] = x[row, ppos[s]*16+k] - x[row, pneg[s]*16+k]
// row = (b,o,i) flattened; 256 floats per row = 16 slots x 16 floats = 64 float4.
// One wave64 <-> one row: lane L holds float4 L of the row (sequential, perfectly
// coalesced load AND store). The slot permutation happens IN-REGISTER via __shfl:
// lane L pulls from lane spos[L>>2]*4 + (L&3). No LDS staging, no __syncthreads.
// Permutation argmax decode runs once in a 1-block pre-kernel into d_ws.

#define NSLOTS 16

__global__ void decode_perm_kernel(const float* __restrict__ Ppos,
                                   const float* __restrict__ Pneg,
                                   int* __restrict__ wsi)
{
    const int t = threadIdx.x;
    if (t < 2 * NSLOTS) {
        const float* P = (t < NSLOTS) ? Ppos : Pneg;
        const int row = t & (NSLOTS - 1);
        int idx = 0;
        #pragma unroll
        for (int j = 0; j < NSLOTS; ++j)
            if (P[row * NSLOTS + j] > 0.5f) idx = j;
        wsi[t] = idx;   // wsi[0..15] = ppos, wsi[16..31] = pneg
    }
}

__global__ __launch_bounds__(256) void permute_ws_kernel(
    const float4* __restrict__ x,
    const int* __restrict__ wsi,
    float4* __restrict__ out,
    long total_v4)
{
    const int lane = threadIdx.x & 63;
    const int slot = lane >> 2;   // [0,16)
    const int k4   = lane & 3;    // [0,4)

    // source lanes within the wave for the two gathers (L1-hit int loads)
    const int src_a = (wsi[slot] << 2) | k4;
    const int src_b = (wsi[NSLOTS + slot] << 2) | k4;

    long idx = (long)blockIdx.x * blockDim.x + threadIdx.x;
    const long stride = (long)gridDim.x * blockDim.x;

    for (; idx < total_v4; idx += stride) {
        const float4 v = x[idx];   // lane L == float4 L of this wave's row

        float4 a, b, r;
        a.x = __shfl(v.x, src_a, 64);
        a.y = __shfl(v.y, src_a, 64);
        a.z = __shfl(v.z, src_a, 64);
        a.w = __shfl(v.w, src_a, 64);
        b.x = __shfl(v.x, src_b, 64);
        b.y = __shfl(v.y, src_b, 64);
        b.z = __shfl(v.z, src_b, 64);
        b.w = __shfl(v.w, src_b, 64);

        r.x = a.x - b.x;
        r.y = a.y - b.y;
        r.z = a.z - b.z;
        r.w = a.w - b.w;
        out[idx] = r;   // sequential, perfectly coalesced
    }
}

extern "C" void kernel_launch(void* const* d_in, const int* in_sizes, int n_in,
                              void* d_out, int out_size, void* d_ws, size_t ws_size,
                              hipStream_t stream)
{
    const float4* x    = (const float4*)d_in[0];
    const float*  Ppos = (const float*)d_in[1];
    const float*  Pneg = (const float*)d_in[2];
    float4*       out  = (float4*)d_out;
    int*          wsi  = (int*)d_ws;   // 32 ints of scratch

    const long total_v4 = (long)out_size / 4;   // 8,388,608

    decode_perm_kernel<<<1, 64, 0, stream>>>(Ppos, Pneg, wsi);

    const int block = 256;
    long blocks_needed = (total_v4 + block - 1) / block;   // 32768
    int grid = (int)(blocks_needed > 32768 ? 32768 : blocks_needed);
    permute_ws_kernel<<<grid, block, 0, stream>>>(x, wsi, out, total_v4);
}